// Round 3
// baseline (320.036 us; speedup 1.0000x reference)
//
#include <hip/hip_runtime.h>
#include <float.h>
#include <limits.h>

// Problem constants: B=64, Q=256 proposals, G=64 max GT, C=768 (unused).
#define QN 256
#define GN 64

typedef float fv64 __attribute__((ext_vector_type(64)));

__device__ __forceinline__ double mkdbl(int lo, int hi) { return __hiloint2double(hi, lo); }

// Wave-wide f64 min via DPP (row_shr 1/2/4/8, row_bcast15/31); result in lane 63,
// then broadcast. Invalid-source lanes keep their own value (bound_ctrl=false,
// old=self) which is harmless for min.
__device__ __forceinline__ double wave_min_f64(double mv) {
#define MSTEP(CTRL, RMASK)                                                      \
  {                                                                             \
    int lo  = __double2loint(mv), hi = __double2hiint(mv);                      \
    int nlo = __builtin_amdgcn_update_dpp(lo, lo, CTRL, RMASK, 0xf, false);     \
    int nhi = __builtin_amdgcn_update_dpp(hi, hi, CTRL, RMASK, 0xf, false);     \
    double nv = mkdbl(nlo, nhi);                                                \
    mv = nv < mv ? nv : mv;                                                     \
  }
  MSTEP(0x111, 0xf)  // row_shr:1
  MSTEP(0x112, 0xf)  // row_shr:2
  MSTEP(0x114, 0xf)  // row_shr:4
  MSTEP(0x118, 0xf)  // row_shr:8
  MSTEP(0x142, 0xa)  // row_bcast15
  MSTEP(0x143, 0xc)  // row_bcast31 -> lane 63 global min
#undef MSTEP
  int lo = __builtin_amdgcn_readlane(__double2loint(mv), 63);
  int hi = __builtin_amdgcn_readlane(__double2hiint(mv), 63);
  return mkdbl(lo, hi);
}

// One 64-lane wave per batch; ALL state in registers. Lane t owns columns
// 4t..4t+3 (cost held as four 64-wide register vectors, dynamically indexed by
// the wave-uniform row i -> v_movrels; shortest/v/path/SC/row4col in scalars)
// and row t (u/col4row/SR). Exact JV semantics (f64, numpy op order) so the
// assignment matches the reference bitwise.
__global__ __launch_bounds__(64, 1) void matcher_kernel(
    const float* __restrict__ gious,   // [B, Q, G]
    const int*   __restrict__ nactual, // [B]
    float*       __restrict__ out,     // [2*B*Q]
    int B)
{
  const int b = blockIdx.x;
  const int t = threadIdx.x;

  int nb = nactual[b];
  nb = nb < 0 ? 0 : (nb > GN ? GN : nb);

  // ---- stage cost into registers: c_k[g] = cost[g][4t+k] = -2*gious[b][4t+k][g]
  // Lane t reads its own 4 rows (q = 4t..4t+3), each 256B contiguous.
  fv64 c0, c1, c2, c3;
  {
    const float* gb = gious + (size_t)b * QN * GN;
#define LOADK(K, CK)                                                            \
    {                                                                           \
      const float4* rp = (const float4*)(gb + (size_t)(4 * t + K) * GN);        \
      _Pragma("unroll")                                                         \
      for (int g4 = 0; g4 < 16; ++g4) {                                         \
        float4 x = rp[g4];                                                      \
        CK[4 * g4 + 0] = -2.0f * x.x;                                           \
        CK[4 * g4 + 1] = -2.0f * x.y;                                           \
        CK[4 * g4 + 2] = -2.0f * x.z;                                           \
        CK[4 * g4 + 3] = -2.0f * x.w;                                           \
      }                                                                         \
    }
    LOADK(0, c0)
    LOADK(1, c1)
    LOADK(2, c2)
    LOADK(3, c3)
#undef LOADK
  }

  // ---- persistent per-lane state ----
  double v0 = 0, v1 = 0, v2 = 0, v3 = 0;          // v[4t..4t+3]
  int r4c0 = -1, r4c1 = -1, r4c2 = -1, r4c3 = -1; // row4col[4t..4t+3]
  double u = 0.0;                                  // u[t]
  int col4row = -1;                                // col4row[t]

  for (int cur = 0; cur < nb; ++cur) {
    double s0 = DBL_MAX, s1 = DBL_MAX, s2 = DBL_MAX, s3 = DBL_MAX; // shortest
    int p0 = -1, p1 = -1, p2 = -1, p3 = -1;                         // path
    int scm = 0;  // SC bits for my 4 columns
    int sr  = 0;  // SR flag for my row
    double min_val = 0.0;
    int i = cur;
    int sink = -1;

    while (sink < 0) {
      // cost row i, my 4 columns — register-indexed (v_movrels), i wave-uniform
      int iu = __builtin_amdgcn_readfirstlane(i);
      float cx = c0[iu], cy = c1[iu], cz = c2[iu], cw = c3[iu];
      if (t == iu) sr = 1;
      // u[i] broadcast
      double u_i = mkdbl(__builtin_amdgcn_readlane(__double2loint(u), iu),
                         __builtin_amdgcn_readlane(__double2hiint(u), iu));
      // relax (numpy op order: ((min_val + c) - u_i) - v)
      double r;
      r = ((min_val + (double)cx) - u_i) - v0; if (!(scm & 1) && r < s0) { s0 = r; p0 = iu; }
      r = ((min_val + (double)cy) - u_i) - v1; if (!(scm & 2) && r < s1) { s1 = r; p1 = iu; }
      r = ((min_val + (double)cz) - u_i) - v2; if (!(scm & 4) && r < s2) { s2 = r; p2 = iu; }
      r = ((min_val + (double)cw) - u_i) - v3; if (!(scm & 8) && r < s3) { s3 = r; p3 = iu; }
      // masked values for the min
      double sp0 = (scm & 1) ? DBL_MAX : s0;
      double sp1 = (scm & 2) ? DBL_MAX : s1;
      double sp2 = (scm & 4) ? DBL_MAX : s2;
      double sp3 = (scm & 8) ? DBL_MAX : s3;
      double m01 = sp1 < sp0 ? sp1 : sp0;
      double m23 = sp3 < sp2 ? sp3 : sp2;
      double mloc = m23 < m01 ? m23 : m01;
      // global min value, then first (smallest) column index achieving it
      double mv = wave_min_f64(mloc);
      int bj = INT_MAX;
      if (sp3 == mv) bj = 4 * t + 3;
      if (sp2 == mv) bj = 4 * t + 2;
      if (sp1 == mv) bj = 4 * t + 1;
      if (sp0 == mv) bj = 4 * t + 0;
      unsigned long long ball = __ballot(bj != INT_MAX);
      int fl = (int)__builtin_ctzll(ball);
      int jstar = __builtin_amdgcn_readlane(bj, fl);
      min_val = mv;
      int jo = jstar >> 2, sl = jstar & 3;
      // r4 = row4col[jstar]
      int rsel = (sl == 0) ? r4c0 : (sl == 1) ? r4c1 : (sl == 2) ? r4c2 : r4c3;
      int r4 = __builtin_amdgcn_readlane(rsel, jo);
      // SC[jstar] = 1
      if (t == jo) scm |= (1 << sl);
      if (r4 < 0) sink = jstar;
      else        i = r4;
    }

    // ---- dual update (reference order; final shortest, pre-augment col4row)
    {
      int c  = col4row < 0 ? 0 : col4row;
      int ow = (c >> 2) & 63, sl2 = c & 3;
      double g0 = __shfl(s0, ow, 64);
      double g1 = __shfl(s1, ow, 64);
      double g2 = __shfl(s2, ow, 64);
      double g3 = __shfl(s3, ow, 64);
      double s_c = (sl2 == 0) ? g0 : (sl2 == 1) ? g1 : (sl2 == 2) ? g2 : g3;
      if (t == cur)  u += min_val;
      else if (sr)   u += min_val - s_c;
      if (scm & 1) v0 -= min_val - s0;
      if (scm & 2) v1 -= min_val - s1;
      if (scm & 4) v2 -= min_val - s2;
      if (scm & 8) v3 -= min_val - s3;
    }

    // ---- augment along alternating path (uniform walk, lockstep)
    {
      int j = sink;
      while (true) {
        int jo = j >> 2, sl = j & 3;
        int pv = (sl == 0) ? p0 : (sl == 1) ? p1 : (sl == 2) ? p2 : p3;
        int pi = __builtin_amdgcn_readlane(pv, jo);
        if (t == jo) {
          if      (sl == 0) r4c0 = pi;
          else if (sl == 1) r4c1 = pi;
          else if (sl == 2) r4c2 = pi;
          else              r4c3 = pi;
        }
        int jn = __builtin_amdgcn_readlane(col4row, pi);
        if (t == pi) col4row = j;
        j = jn;
        if (pi == cur) break;
      }
    }
  }

  // ---- outputs (every element written -> poison-safe) ----
  {
    const size_t BQ = (size_t)B * QN;
    int base = b * QN + 4 * t;
    float4 inds = make_float4(r4c0 >= 0 ? (float)r4c0 : 0.0f,
                              r4c1 >= 0 ? (float)r4c1 : 0.0f,
                              r4c2 >= 0 ? (float)r4c2 : 0.0f,
                              r4c3 >= 0 ? (float)r4c3 : 0.0f);
    float4 mask = make_float4(r4c0 >= 0 ? 1.0f : 0.0f,
                              r4c1 >= 0 ? 1.0f : 0.0f,
                              r4c2 >= 0 ? 1.0f : 0.0f,
                              r4c3 >= 0 ? 1.0f : 0.0f);
    *(float4*)&out[base]      = inds;
    *(float4*)&out[BQ + base] = mask;
  }
}

extern "C" void kernel_launch(void* const* d_in, const int* in_sizes, int n_in,
                              void* d_out, int out_size, void* d_ws, size_t ws_size,
                              hipStream_t stream) {
  // inputs: 0 last_sem_cls_scores (unused), 1 gious [B,Q,G], 2 positive_map (unused),
  //         3 sem_cls_label (unused), 4 nactual_gt [B]
  const float* gious   = (const float*)d_in[1];
  const int*   nactual = (const int*)d_in[4];
  float*       out     = (float*)d_out;
  const int B = in_sizes[4];

  matcher_kernel<<<B, 64, 0, stream>>>(gious, nactual, out, B);
}

// Round 4
// 151.207 us; speedup vs baseline: 2.1165x; 2.1165x over previous
//
#include <hip/hip_runtime.h>
#include <float.h>
#include <limits.h>

// Problem constants: B=64, Q=256 proposals, G=64 max GT, C=768 (unused).
#define QN 256
#define GN 64

typedef float fv64 __attribute__((ext_vector_type(64)));

__device__ __forceinline__ double mkdbl(int lo, int hi) { return __hiloint2double(hi, lo); }

// Wave-wide f64 min via DPP (row_shr 1/2/4/8, row_bcast15/31) using v_min_f64
// per step; result lands in lane 63, then broadcast via readlane.
__device__ __forceinline__ double wave_min_f64(double mv) {
#define MSTEP(CTRL, RMASK)                                                      \
  {                                                                             \
    int lo  = __double2loint(mv), hi = __double2hiint(mv);                      \
    int nlo = __builtin_amdgcn_update_dpp(lo, lo, CTRL, RMASK, 0xf, false);     \
    int nhi = __builtin_amdgcn_update_dpp(hi, hi, CTRL, RMASK, 0xf, false);     \
    mv = fmin(mv, mkdbl(nlo, nhi));                                             \
  }
  MSTEP(0x111, 0xf)  // row_shr:1
  MSTEP(0x112, 0xf)  // row_shr:2
  MSTEP(0x114, 0xf)  // row_shr:4
  MSTEP(0x118, 0xf)  // row_shr:8
  MSTEP(0x142, 0xa)  // row_bcast15
  MSTEP(0x143, 0xc)  // row_bcast31 -> lane 63 has the global min
#undef MSTEP
  int lo = __builtin_amdgcn_readlane(__double2loint(mv), 63);
  int hi = __builtin_amdgcn_readlane(__double2hiint(mv), 63);
  return mkdbl(lo, hi);
}

// One 64-lane wave per batch; ALL state in registers. Lane t owns columns
// 4t..4t+3; cost lives in four 64-wide register vectors indexed ONLY by
// compile-time constants (uniform switch on row i -> static extracts; rule #20:
// runtime indexing would go to scratch). Exact JV semantics (f64, numpy op
// order) so the assignment matches the reference bitwise.
__global__ __launch_bounds__(64, 1) void matcher_kernel(
    const float* __restrict__ gious,   // [B, Q, G]
    const int*   __restrict__ nactual, // [B]
    float*       __restrict__ out,     // [2*B*Q]
    int B)
{
  const int b = blockIdx.x;
  const int t = threadIdx.x;

  int nb = nactual[b];
  nb = nb < 0 ? 0 : (nb > GN ? GN : nb);

  // ---- stage cost into registers: c_k[g] = cost[g][4t+k] = -2*gious[b][4t+k][g]
  fv64 c0, c1, c2, c3;
  {
    const float* gb = gious + (size_t)b * QN * GN;
#define LOADK(K, CK)                                                            \
    {                                                                           \
      const float4* rp = (const float4*)(gb + (size_t)(4 * t + K) * GN);        \
      _Pragma("unroll")                                                         \
      for (int g4 = 0; g4 < 16; ++g4) {                                         \
        float4 x = rp[g4];                                                      \
        CK[4 * g4 + 0] = -2.0f * x.x;                                           \
        CK[4 * g4 + 1] = -2.0f * x.y;                                           \
        CK[4 * g4 + 2] = -2.0f * x.z;                                           \
        CK[4 * g4 + 3] = -2.0f * x.w;                                           \
      }                                                                         \
    }
    LOADK(0, c0)
    LOADK(1, c1)
    LOADK(2, c2)
    LOADK(3, c3)
#undef LOADK
  }

  // ---- persistent per-lane state ----
  double v0 = 0, v1 = 0, v2 = 0, v3 = 0;          // v[4t..4t+3]
  int r4c0 = -1, r4c1 = -1, r4c2 = -1, r4c3 = -1; // row4col[4t..4t+3]
  double u = 0.0;                                  // u[t]
  int col4row = -1;                                // col4row[t]

  for (int cur = 0; cur < nb; ++cur) {
    double s0 = DBL_MAX, s1 = DBL_MAX, s2 = DBL_MAX, s3 = DBL_MAX;     // shortest
    double sp0 = DBL_MAX, sp1 = DBL_MAX, sp2 = DBL_MAX, sp3 = DBL_MAX; // SC-masked copy
    int p0 = -1, p1 = -1, p2 = -1, p3 = -1;                            // path
    int scm = 0;  // SC bits for my 4 columns
    int sr  = 0;  // SR flag for my row
    double min_val = 0.0;
    int i = cur;
    int sink = -1;

    while (sink < 0) {
      int iu = __builtin_amdgcn_readfirstlane(i);
      // cost row iu, my 4 columns — uniform switch, static extracts only
      float cx, cy, cz, cw;
      switch (iu) {
#define CASEK(K) case (K): cx = c0[(K)]; cy = c1[(K)]; cz = c2[(K)]; cw = c3[(K)]; break;
#define C8(Bse) CASEK((Bse)+0) CASEK((Bse)+1) CASEK((Bse)+2) CASEK((Bse)+3) \
                CASEK((Bse)+4) CASEK((Bse)+5) CASEK((Bse)+6) CASEK((Bse)+7)
        C8(0) C8(8) C8(16) C8(24) C8(32) C8(40) C8(48) C8(56)
#undef C8
#undef CASEK
        default: cx = cy = cz = cw = 0.0f; break;
      }
      if (t == iu) sr = 1;
      // u[i] broadcast
      double u_i = mkdbl(__builtin_amdgcn_readlane(__double2loint(u), iu),
                         __builtin_amdgcn_readlane(__double2hiint(u), iu));
      // relax (numpy op order: ((min_val + c) - u_i) - v)
      double r;
      r = ((min_val + (double)cx) - u_i) - v0; if (!(scm & 1) && r < s0) { s0 = r; sp0 = r; p0 = iu; }
      r = ((min_val + (double)cy) - u_i) - v1; if (!(scm & 2) && r < s1) { s1 = r; sp1 = r; p1 = iu; }
      r = ((min_val + (double)cz) - u_i) - v2; if (!(scm & 4) && r < s2) { s2 = r; sp2 = r; p2 = iu; }
      r = ((min_val + (double)cw) - u_i) - v3; if (!(scm & 8) && r < s3) { s3 = r; sp3 = r; p3 = iu; }
      // local min over my non-SC slots (sp_k = DBL_MAX once k enters SC)
      double mloc = fmin(fmin(sp0, sp1), fmin(sp2, sp3));
      // global min value, then smallest column index achieving it (np tie-break)
      double mv = wave_min_f64(mloc);
      int bj = INT_MAX;
      if (sp3 == mv) bj = 4 * t + 3;
      if (sp2 == mv) bj = 4 * t + 2;
      if (sp1 == mv) bj = 4 * t + 1;
      if (sp0 == mv) bj = 4 * t + 0;
      unsigned long long ball = __ballot(bj != INT_MAX);
      int fl = (int)__builtin_ctzll(ball);
      int jstar = __builtin_amdgcn_readlane(bj, fl);
      min_val = mv;
      int jo = jstar >> 2, sl = jstar & 3;
      // r4 = row4col[jstar]
      int rsel = (sl == 0) ? r4c0 : (sl == 1) ? r4c1 : (sl == 2) ? r4c2 : r4c3;
      int r4 = __builtin_amdgcn_readlane(rsel, jo);
      // SC[jstar] = 1 (and mask its sp)
      if (t == jo) {
        scm |= (1 << sl);
        if      (sl == 0) sp0 = DBL_MAX;
        else if (sl == 1) sp1 = DBL_MAX;
        else if (sl == 2) sp2 = DBL_MAX;
        else              sp3 = DBL_MAX;
      }
      if (r4 < 0) sink = jstar;
      else        i = r4;
    }

    // ---- dual update (reference order; real shortest, pre-augment col4row)
    {
      int c  = col4row < 0 ? 0 : col4row;
      int ow = (c >> 2) & 63, sl2 = c & 3;
      double g0 = __shfl(s0, ow, 64);
      double g1 = __shfl(s1, ow, 64);
      double g2 = __shfl(s2, ow, 64);
      double g3 = __shfl(s3, ow, 64);
      double s_c = (sl2 == 0) ? g0 : (sl2 == 1) ? g1 : (sl2 == 2) ? g2 : g3;
      if (t == cur)  u += min_val;
      else if (sr)   u += min_val - s_c;
      if (scm & 1) v0 -= min_val - s0;
      if (scm & 2) v1 -= min_val - s1;
      if (scm & 4) v2 -= min_val - s2;
      if (scm & 8) v3 -= min_val - s3;
    }

    // ---- augment along alternating path (uniform walk, lockstep)
    {
      int j = sink;
      while (true) {
        int jo = j >> 2, sl = j & 3;
        int pv = (sl == 0) ? p0 : (sl == 1) ? p1 : (sl == 2) ? p2 : p3;
        int pi = __builtin_amdgcn_readlane(pv, jo);
        if (t == jo) {
          if      (sl == 0) r4c0 = pi;
          else if (sl == 1) r4c1 = pi;
          else if (sl == 2) r4c2 = pi;
          else              r4c3 = pi;
        }
        int jn = __builtin_amdgcn_readlane(col4row, pi);
        if (t == pi) col4row = j;
        j = jn;
        if (pi == cur) break;
      }
    }
  }

  // ---- outputs (every element written -> poison-safe) ----
  {
    const size_t BQ = (size_t)B * QN;
    int base = b * QN + 4 * t;
    float4 inds = make_float4(r4c0 >= 0 ? (float)r4c0 : 0.0f,
                              r4c1 >= 0 ? (float)r4c1 : 0.0f,
                              r4c2 >= 0 ? (float)r4c2 : 0.0f,
                              r4c3 >= 0 ? (float)r4c3 : 0.0f);
    float4 mask = make_float4(r4c0 >= 0 ? 1.0f : 0.0f,
                              r4c1 >= 0 ? 1.0f : 0.0f,
                              r4c2 >= 0 ? 1.0f : 0.0f,
                              r4c3 >= 0 ? 1.0f : 0.0f);
    *(float4*)&out[base]      = inds;
    *(float4*)&out[BQ + base] = mask;
  }
}

extern "C" void kernel_launch(void* const* d_in, const int* in_sizes, int n_in,
                              void* d_out, int out_size, void* d_ws, size_t ws_size,
                              hipStream_t stream) {
  // inputs: 0 last_sem_cls_scores (unused), 1 gious [B,Q,G], 2 positive_map (unused),
  //         3 sem_cls_label (unused), 4 nactual_gt [B]
  const float* gious   = (const float*)d_in[1];
  const int*   nactual = (const int*)d_in[4];
  float*       out     = (float*)d_out;
  const int B = in_sizes[4];

  matcher_kernel<<<B, 64, 0, stream>>>(gious, nactual, out, B);
}